// Round 7
// baseline (135.540 us; speedup 1.0000x reference)
//
#include <hip/hip_runtime.h>

// Problem constants (from reference)
#define Bv   8
#define Kv   2048
#define Sv   1024
#define Hv   256      // elements per row; 64 lanes x 4 each
#define Wv   24
#define WINv 3
#define RB   8        // row batch: 8 outstanding loads per wave
#define REPS 4        // MEASUREMENT: in-dispatch repetitions (idempotent)

#define NSPAN (Bv * Kv)

// clang-native 4xfloat vector: __builtin_nontemporal_store requires a real
// vector type (HIP's float4 is a class and is rejected).
typedef float f32x4 __attribute__((ext_vector_type(4)));

__device__ __forceinline__ float bf16_to_f32(unsigned short u) {
    union { unsigned int i; float f; } c;
    c.i = ((unsigned int)u) << 16;
    return c.f;
}

__device__ __forceinline__ void nt_store4(f32x4* p, float a, float b, float c, float d) {
    f32x4 v = { a, b, c, d };
    __builtin_nontemporal_store(v, p);
}

// One wave (64 lanes) per span; lane owns elements [4*lane, 4*lane+4).
// Block = 256 threads = 4 waves = 4 spans (R3-proven structure).
// MEASUREMENT ROUND: body repeated REPS=4x inside ONE dispatch so the kernel
// gets its own rocprof counter row (single launches sit below the ~44 us
// fill cutoff and are invisible). A per-rep asm-opaque zero offset (rz) is
// added to load AND store addresses: compiler cannot CSE row loads across
// reps nor dead-store-eliminate reps 0..2 -> true 4x memory traffic.
// Counter row then reveals: write-BW-bound (hbm_gbps high) vs latency-bound
// (all low). dur_us is sacrificial this round (~120-130 expected).
__global__ __launch_bounds__(256) void span_rep_kernel(
    const void* __restrict__ token_reps,
    const int* __restrict__ span_ids,
    const void* __restrict__ span_masks,
    float* __restrict__ out)
{
    __shared__ int s_tok32;   // 1 if token_reps is fp32, 0 if bf16
    __shared__ int s_ids64;   // 1 if span_ids is int64
    __shared__ int s_maskw;   // 0 uchar, 1 int32, 2 int64, 3 fp32

    const int tid = threadIdx.x;
    if (tid < 64) {
        const unsigned short* tu = (const unsigned short*)token_reps;
        int e = (tu[2 * tid] >> 7) & 0xFF;
        unsigned long long votes = __ballot(e >= 96 && e <= 144);

        const unsigned char* mb = (const unsigned char*)span_masks;
        unsigned char bnz = mb[tid] | mb[tid + 64];
        int m4 = tid & 3;
        unsigned long long z1  = __ballot(bnz && m4 == 1);                    // uchar
        unsigned long long z23 = __ballot(bnz && (m4 == 2 || m4 == 3));       // fp32
        unsigned long long z84 = __ballot(bnz && m4 == 0 && (tid & 7) == 4);  // int32

        if (tid == 0) {
            s_tok32 = (__popcll(votes) >= 56) ? 0 : 1;
            s_maskw = z1 ? 0 : (z23 ? 3 : (z84 ? 1 : 2));
            int odd_or = span_ids[1] | span_ids[3] | span_ids[5] | span_ids[7];
            s_ids64 = (odd_or == 0) ? 1 : 0;
        }
    }
    __syncthreads();

    // XCD-locality swizzle: batch = blockIdx&7 (one batch per XCD),
    // k = (blockIdx>>3)*4 + wave. 4096 blocks cover all 16384 spans.
    const int b    = blockIdx.x & 7;
    const int k    = ((blockIdx.x >> 3) << 2) + (tid >> 6);
    const int span = b * Kv + k;
    const int lane = tid & 63;

    f32x4* out4 = (f32x4*)(out + (size_t)span * (3 * Hv)) + lane;

    // --- decode mask (wave-uniform) ---
    int mv;
    if (s_maskw == 0)      mv = ((const unsigned char*)span_masks)[span];
    else if (s_maskw == 1) mv = ((const int*)span_masks)[span];
    else if (s_maskw == 2) mv = ((const int*)span_masks)[2 * span];
    else                   mv = (((const float*)span_masks)[span] != 0.0f);

    // --- decode ids (wave-uniform) ---
    int start, end;
    if (!s_ids64) {
        start = span_ids[2 * span];
        end   = span_ids[2 * span + 1];
    } else {
        start = span_ids[4 * span];       // lo word of int64 elem 2*span
        end   = span_ids[4 * span + 2];   // lo word of int64 elem 2*span+1
    }
    const int w = end - start;

    const bool invalid = (mv == 0 || w < 1 || w > Wv || start < 0 || end > Sv);

    const size_t row0 = ((size_t)b * Sv + start) * Hv;

    const int  scut      = (w < WINv) ? w : WINv;            // start rows [0, scut)
    const int  ecut      = (w - WINv > 0) ? (w - WINv) : 0;  // end rows [ecut, w)
    const bool has_inner = (w > 2 * WINv);                   // inner rows [WIN, w-WIN)
    const int  icut      = w - WINv;

    for (int rep = 0; rep < REPS; ++rep) {
        // Opaque zero: defeats load-CSE and dead-store-elimination across reps.
        unsigned rz = 0;
        asm volatile("" : "+v"(rz));
        f32x4* o4 = out4 + rz;

        if (invalid) {
            nt_store4(o4,          0.f, 0.f, 0.f, 0.f);   // start section
            nt_store4(o4 + Hv / 4, 0.f, 0.f, 0.f, 0.f);   // inner section
            nt_store4(o4 + Hv / 2, 0.f, 0.f, 0.f, 0.f);   // end section
            continue;
        }

        float s0 = -INFINITY, s1 = -INFINITY, s2 = -INFINITY, s3 = -INFINITY;
        float e0 = -INFINITY, e1 = -INFINITY, e2 = -INFINITY, e3 = -INFINITY;
        float i0 = -INFINITY, i1 = -INFINITY, i2 = -INFINITY, i3 = -INFINITY;

        // Batched row loop (R3 structure): RB outstanding loads, consumed in
        // issue order -> incremental vmcnt waits. Guards wave-uniform.
        if (s_tok32) {
            const float* bp = (const float*)token_reps + row0 + lane * 4 + rz;
            for (int r0 = 0; r0 < w; r0 += RB, bp += RB * Hv) {
                const int n = ((w - r0) < RB) ? (w - r0) : RB;
                float4 buf[RB];
                #pragma unroll
                for (int j = 0; j < RB; ++j)
                    if (j < n) buf[j] = *(const float4*)(bp + j * Hv);
                #pragma unroll
                for (int j = 0; j < RB; ++j) {
                    if (j < n) {
                        const int r = r0 + j;
                        float4 f = buf[j];
                        if (r < scut) {
                            s0 = fmaxf(s0, f.x); s1 = fmaxf(s1, f.y);
                            s2 = fmaxf(s2, f.z); s3 = fmaxf(s3, f.w);
                        }
                        if (r >= ecut) {
                            e0 = fmaxf(e0, f.x); e1 = fmaxf(e1, f.y);
                            e2 = fmaxf(e2, f.z); e3 = fmaxf(e3, f.w);
                        }
                        if (has_inner && r >= WINv && r < icut) {
                            i0 = fmaxf(i0, f.x); i1 = fmaxf(i1, f.y);
                            i2 = fmaxf(i2, f.z); i3 = fmaxf(i3, f.w);
                        }
                    }
                }
            }
        } else {
            const unsigned short* bp = (const unsigned short*)token_reps + row0 + lane * 4 + rz;
            for (int r0 = 0; r0 < w; r0 += RB, bp += RB * Hv) {
                const int n = ((w - r0) < RB) ? (w - r0) : RB;
                ushort4 buf[RB];
                #pragma unroll
                for (int j = 0; j < RB; ++j)
                    if (j < n) buf[j] = *(const ushort4*)(bp + j * Hv);
                #pragma unroll
                for (int j = 0; j < RB; ++j) {
                    if (j < n) {
                        const int r = r0 + j;
                        float f0 = bf16_to_f32(buf[j].x), f1 = bf16_to_f32(buf[j].y);
                        float f2 = bf16_to_f32(buf[j].z), f3 = bf16_to_f32(buf[j].w);
                        if (r < scut) {
                            s0 = fmaxf(s0, f0); s1 = fmaxf(s1, f1);
                            s2 = fmaxf(s2, f2); s3 = fmaxf(s3, f3);
                        }
                        if (r >= ecut) {
                            e0 = fmaxf(e0, f0); e1 = fmaxf(e1, f1);
                            e2 = fmaxf(e2, f2); e3 = fmaxf(e3, f3);
                        }
                        if (has_inner && r >= WINv && r < icut) {
                            i0 = fmaxf(i0, f0); i1 = fmaxf(i1, f1);
                            i2 = fmaxf(i2, f2); i3 = fmaxf(i3, f3);
                        }
                    }
                }
            }
        }
        if (!has_inner) { i0 = s0; i1 = s1; i2 = s2; i3 = s3; }  // no_inner -> start

        nt_store4(o4,          s0, s1, s2, s3);   // start
        nt_store4(o4 + Hv / 4, i0, i1, i2, i3);   // inner
        nt_store4(o4 + Hv / 2, e0, e1, e2, e3);   // end
    }
}

extern "C" void kernel_launch(void* const* d_in, const int* in_sizes, int n_in,
                              void* d_out, int out_size, void* d_ws, size_t ws_size,
                              hipStream_t stream) {
    // Identify inputs by element count (robust to ordering changes):
    // token_reps = 2,097,152; span_ids = 65,536; span_masks = 16,384.
    const void* token_reps = d_in[0];
    const int*  span_ids   = (const int*)d_in[1];
    const void* span_masks = d_in[2];
    for (int i = 0; i < n_in; ++i) {
        if (in_sizes[i] == Bv * Sv * Hv)      token_reps = d_in[i];
        else if (in_sizes[i] == Bv * Kv * 2)  span_ids   = (const int*)d_in[i];
        else if (in_sizes[i] == Bv * Kv)      span_masks = d_in[i];
    }
    float* out = (float*)d_out;

    // 16384 spans, 4 spans (waves) per 256-thread block. Single dispatch;
    // REPS=4 internal repetitions make the kernel visible in rocprof top-5.
    dim3 grid(NSPAN / 4);
    dim3 block(256);
    span_rep_kernel<<<grid, block, 0, stream>>>(token_reps, span_ids, span_masks, out);
}

// Round 8
// 88.643 us; speedup vs baseline: 1.5291x; 1.5291x over previous
//
#include <hip/hip_runtime.h>

// Problem constants (from reference)
#define Bv   8
#define Kv   2048
#define Sv   1024
#define Hv   256      // elements per row; 64 lanes x 4 each
#define Wv   24
#define WINv 3
#define RBI  9        // inner-loop row batch (inner region <= 18 rows -> <=2 batches)

#define NSPAN (Bv * Kv)

// clang-native 4xfloat vector: __builtin_nontemporal_store requires a real
// vector type (HIP's float4 is a class and is rejected).
typedef float f32x4 __attribute__((ext_vector_type(4)));

__device__ __forceinline__ void nt_store4(f32x4* p, float a, float b, float c, float d) {
    f32x4 v = { a, b, c, d };
    __builtin_nontemporal_store(v, p);
}

// Convert 4 packed bf16 (as uint2) to 4 f32. Elements: u.x lo, u.x hi,
// u.y lo, u.y hi (memory order). 2 shifts + 2 ands.
__device__ __forceinline__ void bf16x4_to_f32(uint2 u, float& f0, float& f1,
                                              float& f2, float& f3) {
    union { unsigned i; float f; } a, b, c, d;
    a.i = u.x << 16;
    b.i = u.x & 0xFFFF0000u;
    c.i = u.y << 16;
    d.i = u.y & 0xFFFF0000u;
    f0 = a.f; f1 = b.f; f2 = c.f; f3 = d.f;
}

// One wave (64 lanes) per span; lane owns elements [4*lane, 4*lane+4).
// Block = 256 threads = 4 waves = 4 spans. Output fp32 [B,K,3H].
// XCD swizzle: b = blockIdx&7 (one batch per XCD; token slice L2-resident).
// NT stores: output is write-once, never re-read.
//
// R7 counters (REPS=4 row): hbm 29% peak, FETCH ~4 MB (reads L2-resident),
// VALUBusy 43%, Occ 25% -> VALU/latency-bound, NOT BW-bound. Cause: the old
// single loop predicated ALL THREE region updates per row (~28 VALU/row).
// R8: three separate loops (start<=3 rows, inner, end<=3 rows) with
// wave-uniform bounds hoisted to SGPRs (readfirstlane) -> scalar branches,
// per row = 1 load + 4 cvt + 4 max (~8 VALU). Rows load twice only when
// regions overlap (w<6; L2-hit, cheap).
__global__ __launch_bounds__(256) void span_rep_kernel(
    const void* __restrict__ token_reps,
    const int* __restrict__ span_ids,
    const void* __restrict__ span_masks,
    float* __restrict__ out)
{
    __shared__ int s_tok32;   // 1 if token_reps is fp32, 0 if bf16
    __shared__ int s_ids64;   // 1 if span_ids is int64
    __shared__ int s_maskw;   // 0 uchar, 1 int32, 2 int64, 3 fp32

    const int tid = threadIdx.x;
    if (tid < 64) {
        // token width: even-index ushorts of bf16 normals have exponent
        // field in a narrow band; of fp32 they are random mantissa bits.
        const unsigned short* tu = (const unsigned short*)token_reps;
        int e = (tu[2 * tid] >> 7) & 0xFF;
        unsigned long long votes = __ballot(e >= 96 && e <= 144);

        // mask width from nonzero byte positions (~90% True density).
        const unsigned char* mb = (const unsigned char*)span_masks;
        unsigned char bnz = mb[tid] | mb[tid + 64];
        int m4 = tid & 3;
        unsigned long long z1  = __ballot(bnz && m4 == 1);                    // uchar
        unsigned long long z23 = __ballot(bnz && (m4 == 2 || m4 == 3));       // fp32
        unsigned long long z84 = __ballot(bnz && m4 == 0 && (tid & 7) == 4);  // int32

        if (tid == 0) {
            s_tok32 = (__popcll(votes) >= 56) ? 0 : 1;
            s_maskw = z1 ? 0 : (z23 ? 3 : (z84 ? 1 : 2));
            // ids: int32-interleaved => odd slots are ends (>=1);
            // int64 => odd int32 slots are hi-words of values <1024 => zero.
            int odd_or = span_ids[1] | span_ids[3] | span_ids[5] | span_ids[7];
            s_ids64 = (odd_or == 0) ? 1 : 0;
        }
    }
    __syncthreads();

    // XCD-locality swizzle: batch = blockIdx&7 (one batch per XCD),
    // k = (blockIdx>>3)*4 + wave. 4096 blocks cover all 16384 spans.
    const int b    = blockIdx.x & 7;
    const int k    = ((blockIdx.x >> 3) << 2) + (tid >> 6);
    const int span = b * Kv + k;
    const int lane = tid & 63;

    f32x4* out4 = (f32x4*)(out + (size_t)span * (3 * Hv)) + lane;

    // --- decode mask (wave-uniform) ---
    int mv;
    if (s_maskw == 0)      mv = ((const unsigned char*)span_masks)[span];
    else if (s_maskw == 1) mv = ((const int*)span_masks)[span];
    else if (s_maskw == 2) mv = ((const int*)span_masks)[2 * span];
    else                   mv = (((const float*)span_masks)[span] != 0.0f);

    // --- decode ids (wave-uniform) ---
    int start, end;
    if (!s_ids64) {
        start = span_ids[2 * span];
        end   = span_ids[2 * span + 1];
    } else {
        start = span_ids[4 * span];       // lo word of int64 elem 2*span
        end   = span_ids[4 * span + 2];   // lo word of int64 elem 2*span+1
    }

    // Values are uniform across the wave -> hoist to SGPRs. All region
    // bounds/branches below become scalar (s_cmp/s_cbranch), and load
    // addresses become SGPR-base + lane offset.
    start = __builtin_amdgcn_readfirstlane(start);
    end   = __builtin_amdgcn_readfirstlane(end);
    mv    = __builtin_amdgcn_readfirstlane(mv);
    const int w = end - start;

    // invalid span or insane decode -> zeros (keeps failures finite/diagnosable)
    if (mv == 0 || w < 1 || w > Wv || start < 0 || end > Sv) {
        nt_store4(out4,          0.f, 0.f, 0.f, 0.f);   // start section
        nt_store4(out4 + Hv / 4, 0.f, 0.f, 0.f, 0.f);   // inner section
        nt_store4(out4 + Hv / 2, 0.f, 0.f, 0.f, 0.f);   // end section
        return;
    }

    const int  scut      = (w < WINv) ? w : WINv;        // start rows [0, scut)
    const int  ecut      = (w > WINv) ? (w - WINv) : 0;  // end rows [ecut, w)
    const int  ec        = w - ecut;                     // = min(w, WIN)
    const bool has_inner = (w > 2 * WINv);               // inner rows [WIN, w-WIN)
    const int  icut      = w - WINv;

    const size_t row0 = ((size_t)b * Sv + start) * Hv;

    float s0 = -INFINITY, s1 = -INFINITY, s2 = -INFINITY, s3 = -INFINITY;
    float e0 = -INFINITY, e1 = -INFINITY, e2 = -INFINITY, e3 = -INFINITY;
    float i0 = -INFINITY, i1 = -INFINITY, i2 = -INFINITY, i3 = -INFINITY;

    if (s_tok32) {
        const float* bp = (const float*)token_reps + row0 + lane * 4;
        const float* ep = bp + (size_t)ecut * Hv;

        // start + end rows (<=6): issue all loads, then reduce.
        float4 sb[WINv], eb[WINv];
        #pragma unroll
        for (int j = 0; j < WINv; ++j)
            if (j < scut) sb[j] = *(const float4*)(bp + j * Hv);
        #pragma unroll
        for (int j = 0; j < WINv; ++j)
            if (j < ec)   eb[j] = *(const float4*)(ep + j * Hv);
        #pragma unroll
        for (int j = 0; j < WINv; ++j)
            if (j < scut) {
                s0 = fmaxf(s0, sb[j].x); s1 = fmaxf(s1, sb[j].y);
                s2 = fmaxf(s2, sb[j].z); s3 = fmaxf(s3, sb[j].w);
            }
        #pragma unroll
        for (int j = 0; j < WINv; ++j)
            if (j < ec) {
                e0 = fmaxf(e0, eb[j].x); e1 = fmaxf(e1, eb[j].y);
                e2 = fmaxf(e2, eb[j].z); e3 = fmaxf(e3, eb[j].w);
            }

        // inner rows [WIN, icut): pure load+max, no per-row region tests.
        if (has_inner) {
            const float* ip = bp + WINv * Hv;
            for (int r0 = WINv; r0 < icut; r0 += RBI, ip += RBI * Hv) {
                const int n = ((icut - r0) < RBI) ? (icut - r0) : RBI;
                float4 buf[RBI];
                #pragma unroll
                for (int j = 0; j < RBI; ++j)
                    if (j < n) buf[j] = *(const float4*)(ip + j * Hv);
                #pragma unroll
                for (int j = 0; j < RBI; ++j)
                    if (j < n) {
                        i0 = fmaxf(i0, buf[j].x); i1 = fmaxf(i1, buf[j].y);
                        i2 = fmaxf(i2, buf[j].z); i3 = fmaxf(i3, buf[j].w);
                    }
            }
        }
    } else {
        const unsigned short* bp = (const unsigned short*)token_reps + row0 + lane * 4;
        const unsigned short* ep = bp + (size_t)ecut * Hv;

        uint2 sb[WINv], eb[WINv];
        #pragma unroll
        for (int j = 0; j < WINv; ++j)
            if (j < scut) sb[j] = *(const uint2*)(bp + j * Hv);
        #pragma unroll
        for (int j = 0; j < WINv; ++j)
            if (j < ec)   eb[j] = *(const uint2*)(ep + j * Hv);
        #pragma unroll
        for (int j = 0; j < WINv; ++j)
            if (j < scut) {
                float f0, f1, f2, f3;
                bf16x4_to_f32(sb[j], f0, f1, f2, f3);
                s0 = fmaxf(s0, f0); s1 = fmaxf(s1, f1);
                s2 = fmaxf(s2, f2); s3 = fmaxf(s3, f3);
            }
        #pragma unroll
        for (int j = 0; j < WINv; ++j)
            if (j < ec) {
                float f0, f1, f2, f3;
                bf16x4_to_f32(eb[j], f0, f1, f2, f3);
                e0 = fmaxf(e0, f0); e1 = fmaxf(e1, f1);
                e2 = fmaxf(e2, f2); e3 = fmaxf(e3, f3);
            }

        if (has_inner) {
            const unsigned short* ip = bp + WINv * Hv;
            for (int r0 = WINv; r0 < icut; r0 += RBI, ip += RBI * Hv) {
                const int n = ((icut - r0) < RBI) ? (icut - r0) : RBI;
                uint2 buf[RBI];
                #pragma unroll
                for (int j = 0; j < RBI; ++j)
                    if (j < n) buf[j] = *(const uint2*)(ip + j * Hv);
                #pragma unroll
                for (int j = 0; j < RBI; ++j)
                    if (j < n) {
                        float f0, f1, f2, f3;
                        bf16x4_to_f32(buf[j], f0, f1, f2, f3);
                        i0 = fmaxf(i0, f0); i1 = fmaxf(i1, f1);
                        i2 = fmaxf(i2, f2); i3 = fmaxf(i3, f3);
                    }
            }
        }
    }
    if (!has_inner) { i0 = s0; i1 = s1; i2 = s2; i3 = s3; }  // no_inner -> start

    nt_store4(out4,          s0, s1, s2, s3);   // start
    nt_store4(out4 + Hv / 4, i0, i1, i2, i3);   // inner
    nt_store4(out4 + Hv / 2, e0, e1, e2, e3);   // end
}

extern "C" void kernel_launch(void* const* d_in, const int* in_sizes, int n_in,
                              void* d_out, int out_size, void* d_ws, size_t ws_size,
                              hipStream_t stream) {
    // Identify inputs by element count (robust to ordering changes):
    // token_reps = 2,097,152; span_ids = 65,536; span_masks = 16,384.
    const void* token_reps = d_in[0];
    const int*  span_ids   = (const int*)d_in[1];
    const void* span_masks = d_in[2];
    for (int i = 0; i < n_in; ++i) {
        if (in_sizes[i] == Bv * Sv * Hv)      token_reps = d_in[i];
        else if (in_sizes[i] == Bv * Kv * 2)  span_ids   = (const int*)d_in[i];
        else if (in_sizes[i] == Bv * Kv)      span_masks = d_in[i];
    }
    float* out = (float*)d_out;

    // 16384 spans, 4 spans (waves) per 256-thread block. Single launch.
    dim3 grid(NSPAN / 4);
    dim3 block(256);
    span_rep_kernel<<<grid, block, 0, stream>>>(token_reps, span_ids, span_masks, out);
}